// Round 14
// baseline (242.531 us; speedup 1.0000x reference)
//
#include <hip/hip_runtime.h>
#include <math.h>

#define DEV __device__ __forceinline__

typedef short s16x8 __attribute__((ext_vector_type(8)));
typedef float f32x4 __attribute__((ext_vector_type(4)));
typedef int   i32x4 __attribute__((ext_vector_type(4)));

// ---- ws dword layout ----
// [0..3]: reduction slots (bit patterns of non-negative floats)
static constexpr int W1S = 16;   // 64 per-out-row weight scales
static constexpr int W2S = 80;   // 32
static constexpr int W3S = 112;  // 32
static constexpr int W4S = 144;  // 5
static constexpr int F0  = 256;  // 18 A-fragments (weights), each 64 lanes x int4
// frag ids: 0..3 = A1[nt] | 4..11 = A2[mt*4+c] | 12..15 = A3[mt*2+c] | 16..17 = A4[c]

DEV float qbias(float b, float bs) {
    float q = rintf(b / bs);
    return fminf(fmaxf(q, -2.147483648e9f), 2.147483648e9f);
}

DEV unsigned short bf16b(float f) {  // values used are exact in bf16 -> truncate
    return (unsigned short)(__float_as_uint(f) >> 16);
}

DEV void reduceAndAtomicMax(float v, unsigned int* slot) {
    #pragma unroll
    for (int off = 32; off; off >>= 1) v = fmaxf(v, __shfl_xor(v, off));
    __shared__ float sm[16];
    const int wid = threadIdx.x >> 6;
    if ((threadIdx.x & 63) == 0) sm[wid] = v;
    __syncthreads();
    if (threadIdx.x == 0) {
        const int nw = blockDim.x >> 6;
        float m = sm[0];
        for (int i = 1; i < nw; i++) m = fmaxf(m, sm[i]);
        atomicMax(slot, __float_as_uint(m)); // non-negative: bit order == value order
    }
}

// ---- setup: quantize weights, emit k-permuted A-fragments (weights as MFMA A) ----
__global__ __launch_bounds__(256) void k_quantw(const float* __restrict__ W1,
                                                const float* __restrict__ W2,
                                                const float* __restrict__ W3,
                                                const float* __restrict__ W4,
                                                float* __restrict__ wsf) {
    __shared__ int wq1[64 * 16], wq2[32 * 64], wq3[32 * 32], wq4[5 * 32];
    int* wsi = (int*)wsf;
    const int t = threadIdx.x;
    if (t < 4) ((unsigned int*)wsf)[t] = 0u;

    const float* W = nullptr; int row = -1, cols = 0; int* dq = nullptr; float* dsc = nullptr;
    if (t < 64)       { W = W1; row = t;       cols = 16; dq = wq1 + row * 16; dsc = wsf + W1S + row; }
    else if (t < 96)  { W = W2; row = t - 64;  cols = 64; dq = wq2 + row * 64; dsc = wsf + W2S + row; }
    else if (t < 128) { W = W3; row = t - 96;  cols = 32; dq = wq3 + row * 32; dsc = wsf + W3S + row; }
    else if (t < 133) { W = W4; row = t - 128; cols = 32; dq = wq4 + row * 32; dsc = wsf + W4S + row; }
    if (row >= 0) {
        const float* src = W + row * cols;
        float m = 0.f;
        for (int i = 0; i < cols; i++) m = fmaxf(m, fabsf(src[i]));
        float s = fmaxf(m * (1.0f / 127.0f), 1e-8f);
        *dsc = s;
        for (int i = 0; i < cols; i++) {
            float q = fminf(fmaxf(rintf(src[i] / s), -128.f), 127.f);
            dq[i] = (int)q;
        }
    }
    __syncthreads();

    // A-fragment: lane l holds A[row = l&15][k = (l>>4)*8 + e].
    //  L1: k=8*grp+e -> feature (grp&1)*8 + e           (grp>>1 = hi/lo)
    //  L2/L3/L4 chunk c: k=8*grp+e -> feature 16c + 4*grp + (e&3)  (e>>2 = hi/lo)
    for (int sIdx = t; sIdx < 18 * 64; sIdx += 256) {
        const int f = sIdx >> 6, l = sIdx & 63;
        const int grp = l >> 4, li = l & 15;
        int dw[4];
        #pragma unroll
        for (int d = 0; d < 4; d++) {
            unsigned int hv[2];
            #pragma unroll
            for (int h = 0; h < 2; h++) {
                const int e = 2 * d + h;
                int wv;
                if (f < 4) {
                    wv = wq1[(f * 16 + li) * 16 + (grp & 1) * 8 + e];
                } else if (f < 12) {
                    int mt = (f - 4) >> 2, c = (f - 4) & 3;
                    wv = wq2[(mt * 16 + li) * 64 + 16 * c + 4 * grp + (e & 3)];
                } else if (f < 16) {
                    int mt = (f - 12) >> 1, c = (f - 12) & 1;
                    wv = wq3[(mt * 16 + li) * 32 + 16 * c + 4 * grp + (e & 3)];
                } else {
                    int c = f - 16;
                    wv = (li < 5) ? wq4[li * 32 + 16 * c + 4 * grp + (e & 3)] : 0;
                }
                hv[h] = bf16b((float)wv);
            }
            dw[d] = (int)(hv[0] | (hv[1] << 16));
        }
        ((int4*)(wsi + F0))[f * 64 + l] = make_int4(dw[0], dw[1], dw[2], dw[3]);
    }
}

// ---- K0: max|x| ----
__global__ __launch_bounds__(1024, 4) void k_absmax(const float4* __restrict__ x,
                                                    unsigned int* __restrict__ slots, int n4) {
    float m = 0.f;
    for (int i = blockIdx.x * blockDim.x + threadIdx.x; i < n4; i += gridDim.x * blockDim.x) {
        float4 v = x[i];
        m = fmaxf(m, fmaxf(fmaxf(fabsf(v.x), fabsf(v.y)), fmaxf(fabsf(v.z), fabsf(v.w))));
    }
    reduceAndAtomicMax(m, slots + 0);
}

// pack bf16 bits of two low16-zero floats into one dword: {b0>>16, b1>>16}
DEV int packhi(float q0, float q1) {
    return (int)__builtin_amdgcn_perm(__float_as_uint(q1), __float_as_uint(q0), 0x07060302u);
}

// quant(+relu+clamp via med3) + truncation split, two values -> hi dword + lo dword
DEV void qsplit2(float a0, float a1, float2 c0, float2 c1, int& hw, int& lw) {
    float t0 = fmaf(a0, c0.x, c0.y);
    float t1 = fmaf(a1, c1.x, c1.y);
    float q0 = fminf(fmaxf(rintf(t0), 0.f), 32767.f);      // -> v_med3_f32
    float q1 = fminf(fmaxf(rintf(t1), 0.f), 32767.f);
    float h0 = __uint_as_float(__float_as_uint(q0) & 0xFFFF0000u); // top 8 sig bits
    float h1 = __uint_as_float(__float_as_uint(q1) & 0xFFFF0000u);
    hw = packhi(h0, h1);
    lw = packhi(q0 - h0, q1 - h1);  // residual <= 7 sig bits, bf16-exact
}

// build next-layer B-fragment; per-value consts read fresh from LDS (volatile b128,
// address uniform per 16-lane group -> broadcast; prevents loop-invariant hoisting
// into registers, which was the source of the spills in r8-r12)
DEV s16x8 mkfrag(f32x4 acc, const float2* base) {
    i32x4 wA = *(const volatile i32x4*)(base);       // cq[0], cq[1]
    i32x4 wB = *(const volatile i32x4*)(base + 2);   // cq[2], cq[3]
    int h01, h23, l01, l23;
    qsplit2(acc[0], acc[1],
            make_float2(__int_as_float(wA[0]), __int_as_float(wA[1])),
            make_float2(__int_as_float(wA[2]), __int_as_float(wA[3])), h01, l01);
    qsplit2(acc[2], acc[3],
            make_float2(__int_as_float(wB[0]), __int_as_float(wB[1])),
            make_float2(__int_as_float(wB[2]), __int_as_float(wB[3])), h23, l23);
    return __builtin_bit_cast(s16x8, make_int4(h01, h23, l01, l23));
}

DEV float qxsel(float v, float inv0, bool hi) {
    float q = rintf(v * inv0);
    q = fminf(fmaxf(q, -32768.f), 32767.f);                // -> v_med3_f32
    float h = __uint_as_float(__float_as_uint(q) & 0xFFFF0000u);
    return hi ? h : (q - h);
}

// ---- staged forward (per-wave chain; WPB_/TPW_ set per stage kernel) ----
template <int STAGE, int WPB_, int TPW_>
DEV void stage_body(const float* __restrict__ x,
                    const float* __restrict__ b1, const float* __restrict__ b2,
                    const float* __restrict__ b3, const float* __restrict__ b4,
                    const float* __restrict__ wsf, unsigned int* __restrict__ slots,
                    float* __restrict__ out) {
    __shared__ __align__(16) float2 QA[64], QB[32], QC[32], QD[16];
    const int t = threadIdx.x;
    const int w = t >> 6, l = t & 63;
    const int grp = l >> 4, li = l & 15;

    const float s0 = fmaxf(__uint_as_float(slots[0]) * (1.f / 32767.f), 1e-8f);
    float s1 = 1.f, s2 = 1.f, s3 = 1.f;
    if (STAGE >= 2) s1 = fmaxf(__uint_as_float(slots[1]) * (1.f / 32767.f), 1e-8f);
    if (STAGE >= 3) s2 = fmaxf(__uint_as_float(slots[2]) * (1.f / 32767.f), 1e-8f);
    if (STAGE >= 4) s3 = fmaxf(__uint_as_float(slots[3]) * (1.f / 32767.f), 1e-8f);
    const float inv0 = 1.f / s0;
    const float inv1 = (STAGE >= 2) ? 1.f / s1 : 0.f;
    const float inv2 = (STAGE >= 3) ? 1.f / s2 : 0.f;
    const float inv3 = (STAGE >= 4) ? 1.f / s3 : 0.f;

    if (t < 64) {
        float bs = wsf[W1S + t] * s0; float bi = qbias(b1[t], bs) * bs;
        QA[t] = (STAGE == 1) ? make_float2(bs, bi) : make_float2(bs * inv1, bi * inv1);
    }
    if (STAGE >= 2 && t >= 64 && t < 96) {
        int i = t - 64;
        float bs = wsf[W2S + i] * s1; float bi = qbias(b2[i], bs) * bs;
        QB[i] = (STAGE == 2) ? make_float2(bs, bi) : make_float2(bs * inv2, bi * inv2);
    }
    if (STAGE >= 3 && t >= 96 && t < 128) {
        int i = t - 96;
        float bs = wsf[W3S + i] * s2; float bi = qbias(b3[i], bs) * bs;
        QC[i] = (STAGE == 3) ? make_float2(bs, bi) : make_float2(bs * inv3, bi * inv3);
    }
    if (STAGE >= 4 && t >= 128 && t < 144) {
        int i = t - 128;
        if (i < 5) { float bs = wsf[W4S + i] * s3; QD[i] = make_float2(bs, qbias(b4[i], bs) * bs); }
        else QD[i] = make_float2(0.f, 0.f);
    }
    __syncthreads();

    const int4* fr = (const int4*)((const int*)wsf + F0);
    s16x8 A1[4], A2[2][4], A3[2][2], A4[2];
    #pragma unroll
    for (int nt = 0; nt < 4; nt++) A1[nt] = __builtin_bit_cast(s16x8, fr[nt * 64 + l]);
    if (STAGE >= 2)
        #pragma unroll
        for (int mt = 0; mt < 2; mt++)
            #pragma unroll
            for (int c = 0; c < 4; c++) A2[mt][c] = __builtin_bit_cast(s16x8, fr[(4 + mt * 4 + c) * 64 + l]);
    if (STAGE >= 3)
        #pragma unroll
        for (int mt = 0; mt < 2; mt++)
            #pragma unroll
            for (int c = 0; c < 2; c++) A3[mt][c] = __builtin_bit_cast(s16x8, fr[(12 + mt * 2 + c) * 64 + l]);
    if (STAGE >= 4) {
        A4[0] = __builtin_bit_cast(s16x8, fr[16 * 64 + l]);
        A4[1] = __builtin_bit_cast(s16x8, fr[17 * 64 + l]);
    }

    float ma1[4][4], ma2[2][4], ma3[2][4];
    if (STAGE == 1)
        #pragma unroll
        for (int nt = 0; nt < 4; nt++)
            #pragma unroll
            for (int r = 0; r < 4; r++) ma1[nt][r] = -3.402823466e38f;
    if (STAGE == 2)
        #pragma unroll
        for (int mt = 0; mt < 2; mt++)
            #pragma unroll
            for (int r = 0; r < 4; r++) ma2[mt][r] = -3.402823466e38f;
    if (STAGE == 3)
        #pragma unroll
        for (int mt = 0; mt < 2; mt++)
            #pragma unroll
            for (int r = 0; r < 4; r++) ma3[mt][r] = -3.402823466e38f;

    const bool hiLane = (grp < 2);
    const size_t tile0 = ((size_t)blockIdx.x * WPB_ + w) * (size_t)TPW_;

    // software prefetch of tile 0's x
    float4 px0, px1;
    {
        const float4* xr = (const float4*)(x + (tile0 * 16 + li) * 16 + (grp & 1) * 8);
        px0 = xr[0]; px1 = xr[1];
    }

    for (int it = 0; it < TPW_; ++it) {
        const size_t row0 = (tile0 + it) * 16;
        float4 v0 = px0, v1 = px1;
        if (it + 1 < TPW_) {  // issue next tile's loads early; compute below hides latency
            const float4* xr = (const float4*)(x + ((tile0 + it + 1) * 16 + li) * 16 + (grp & 1) * 8);
            px0 = xr[0]; px1 = xr[1];
        }

        // ---- B1 from x: col=li (batch), k=8*grp+e -> feature 8*(grp&1)+e, hi/lo=grp>>1
        s16x8 b1v;
        {
            float p0 = qxsel(v0.x, inv0, hiLane), p1 = qxsel(v0.y, inv0, hiLane);
            float p2 = qxsel(v0.z, inv0, hiLane), p3 = qxsel(v0.w, inv0, hiLane);
            float p4 = qxsel(v1.x, inv0, hiLane), p5 = qxsel(v1.y, inv0, hiLane);
            float p6 = qxsel(v1.z, inv0, hiLane), p7 = qxsel(v1.w, inv0, hiLane);
            b1v = __builtin_bit_cast(s16x8,
                make_int4(packhi(p0, p1), packhi(p2, p3), packhi(p4, p5), packhi(p6, p7)));
        }

        // ---- L1: D1[nt] lane holds (batch li, feature 16nt+4grp+r) ----
        s16x8 B2f[4];
        #pragma unroll
        for (int nt = 0; nt < 4; nt++) {
            f32x4 acc = {0.f, 0.f, 0.f, 0.f};
            acc = __builtin_amdgcn_mfma_f32_16x16x32_bf16(A1[nt], b1v, acc, 0, 0, 0);
            if constexpr (STAGE == 1) {
                #pragma unroll
                for (int r = 0; r < 4; r++) ma1[nt][r] = fmaxf(ma1[nt][r], acc[r]);
            } else {
                B2f[nt] = mkfrag(acc, QA + 16 * nt + 4 * grp);
            }
        }
        if constexpr (STAGE == 1) continue;

        // ---- L2: chunk c consumes D1-tile nt=c ----
        f32x4 acc2[2] = {{0.f, 0.f, 0.f, 0.f}, {0.f, 0.f, 0.f, 0.f}};
        #pragma unroll
        for (int c = 0; c < 4; c++) {
            acc2[0] = __builtin_amdgcn_mfma_f32_16x16x32_bf16(A2[0][c], B2f[c], acc2[0], 0, 0, 0);
            acc2[1] = __builtin_amdgcn_mfma_f32_16x16x32_bf16(A2[1][c], B2f[c], acc2[1], 0, 0, 0);
        }
        if constexpr (STAGE == 2) {
            #pragma unroll
            for (int mt = 0; mt < 2; mt++)
                #pragma unroll
                for (int r = 0; r < 4; r++) ma2[mt][r] = fmaxf(ma2[mt][r], acc2[mt][r]);
            continue;
        }

        if constexpr (STAGE >= 3) {
            s16x8 B3f[2];
            #pragma unroll
            for (int c = 0; c < 2; c++) B3f[c] = mkfrag(acc2[c], QB + 16 * c + 4 * grp);

            f32x4 acc3[2] = {{0.f, 0.f, 0.f, 0.f}, {0.f, 0.f, 0.f, 0.f}};
            #pragma unroll
            for (int c = 0; c < 2; c++) {
                acc3[0] = __builtin_amdgcn_mfma_f32_16x16x32_bf16(A3[0][c], B3f[c], acc3[0], 0, 0, 0);
                acc3[1] = __builtin_amdgcn_mfma_f32_16x16x32_bf16(A3[1][c], B3f[c], acc3[1], 0, 0, 0);
            }
            if constexpr (STAGE == 3) {
                #pragma unroll
                for (int mt = 0; mt < 2; mt++)
                    #pragma unroll
                    for (int r = 0; r < 4; r++) ma3[mt][r] = fmaxf(ma3[mt][r], acc3[mt][r]);
                continue;
            }

            if constexpr (STAGE == 4) {
                s16x8 B4f[2];
                #pragma unroll
                for (int c = 0; c < 2; c++) B4f[c] = mkfrag(acc3[c], QC + 16 * c + 4 * grp);

                f32x4 acc4 = {0.f, 0.f, 0.f, 0.f};
                acc4 = __builtin_amdgcn_mfma_f32_16x16x32_bf16(A4[0], B4f[0], acc4, 0, 0, 0);
                acc4 = __builtin_amdgcn_mfma_f32_16x16x32_bf16(A4[1], B4f[1], acc4, 0, 0, 0);

                // exit consts read fresh (volatile) as well
                i32x4 wE0 = *(const volatile i32x4*)(QD + 4 * grp);
                i32x4 wE1 = *(const volatile i32x4*)(QD + 4 * grp + 2);
                float lg0 = fmaf(acc4[0], __int_as_float(wE0[0]), __int_as_float(wE0[1]));
                float lg1 = fmaf(acc4[1], __int_as_float(wE0[2]), __int_as_float(wE0[3]));
                float lg2 = fmaf(acc4[2], __int_as_float(wE1[0]), __int_as_float(wE1[1]));
                float lg3 = fmaf(acc4[3], __int_as_float(wE1[2]), __int_as_float(wE1[3]));
                float lg4 = __shfl(lg0, li + 16);  // grp1 reg0 = feature 4

                if (l < 16) {
                    float m = fmaxf(fmaxf(fmaxf(lg0, lg1), fmaxf(lg2, lg3)), lg4);
                    float e0 = __expf(lg0 - m), e1 = __expf(lg1 - m), e2 = __expf(lg2 - m),
                          e3 = __expf(lg3 - m), ee4 = __expf(lg4 - m);
                    float r = 1.f / (e0 + e1 + e2 + e3 + ee4);
                    float* dst = out + (row0 + l) * 5;
                    dst[0] = e0 * r; dst[1] = e1 * r; dst[2] = e2 * r; dst[3] = e3 * r; dst[4] = ee4 * r;
                }
            }
        }
    }

    if (STAGE == 1) {
        float vmax = 0.f;
        #pragma unroll
        for (int nt = 0; nt < 4; nt++)
            #pragma unroll
            for (int r = 0; r < 4; r++) {
                float2 c = QA[16 * nt + 4 * grp + r];
                vmax = fmaxf(vmax, fmaf(ma1[nt][r], c.x, c.y));
            }
        reduceAndAtomicMax(vmax, slots + 1);
    } else if (STAGE == 2) {
        float vmax = 0.f;
        #pragma unroll
        for (int mt = 0; mt < 2; mt++)
            #pragma unroll
            for (int r = 0; r < 4; r++) {
                float2 c = QB[16 * mt + 4 * grp + r];
                vmax = fmaxf(vmax, fmaf(ma2[mt][r], c.x, c.y));
            }
        reduceAndAtomicMax(vmax, slots + 2);
    } else if (STAGE == 3) {
        float vmax = 0.f;
        #pragma unroll
        for (int mt = 0; mt < 2; mt++)
            #pragma unroll
            for (int r = 0; r < 4; r++) {
                float2 c = QC[16 * mt + 4 * grp + r];
                vmax = fmaxf(vmax, fmaf(ma3[mt][r], c.x, c.y));
            }
        reduceAndAtomicMax(vmax, slots + 3);
    }
}

// all stages: 1024-thread blocks; quant consts live in LDS (volatile reads), so
// fragments + working set fit the 128-reg unified budget without spilling
__global__ __launch_bounds__(1024, 4) void k_s1(const float* x, const float* b1, const float* b2,
                                                const float* b3, const float* b4, const float* ws,
                                                unsigned int* slots, float* out) {
    stage_body<1, 16, 8>(x, b1, b2, b3, b4, ws, slots, out);
}
__global__ __launch_bounds__(1024, 4) void k_s2(const float* x, const float* b1, const float* b2,
                                                const float* b3, const float* b4, const float* ws,
                                                unsigned int* slots, float* out) {
    stage_body<2, 16, 8>(x, b1, b2, b3, b4, ws, slots, out);
}
__global__ __launch_bounds__(1024, 4) void k_s3(const float* x, const float* b1, const float* b2,
                                                const float* b3, const float* b4, const float* ws,
                                                unsigned int* slots, float* out) {
    stage_body<3, 16, 8>(x, b1, b2, b3, b4, ws, slots, out);
}
__global__ __launch_bounds__(1024, 4) void k_s4(const float* x, const float* b1, const float* b2,
                                                const float* b3, const float* b4, const float* ws,
                                                unsigned int* slots, float* out) {
    stage_body<4, 16, 8>(x, b1, b2, b3, b4, ws, slots, out);
}

extern "C" void kernel_launch(void* const* d_in, const int* in_sizes, int n_in,
                              void* d_out, int out_size, void* d_ws, size_t ws_size,
                              hipStream_t stream) {
    const float* x  = (const float*)d_in[0];
    const float* W1 = (const float*)d_in[1];
    const float* b1 = (const float*)d_in[2];
    const float* W2 = (const float*)d_in[3];
    const float* b2 = (const float*)d_in[4];
    const float* W3 = (const float*)d_in[5];
    const float* b3 = (const float*)d_in[6];
    const float* W4 = (const float*)d_in[7];
    const float* b4 = (const float*)d_in[8];
    float* out = (float*)d_out;
    float* ws = (float*)d_ws;
    unsigned int* slots = (unsigned int*)d_ws;

    const int B = in_sizes[0] / 16;               // 1 << 20 rows
    const int blocks = B / (16 * 8 * 16);         // 512

    k_quantw<<<1, 256, 0, stream>>>(W1, W2, W3, W4, ws);
    k_absmax<<<512, 1024, 0, stream>>>((const float4*)x, slots, in_sizes[0] / 4);
    k_s1<<<blocks, 1024, 0, stream>>>(x, b1, b2, b3, b4, ws, slots, out);
    k_s2<<<blocks, 1024, 0, stream>>>(x, b1, b2, b3, b4, ws, slots, out);
    k_s3<<<blocks, 1024, 0, stream>>>(x, b1, b2, b3, b4, ws, slots, out);
    k_s4<<<blocks, 1024, 0, stream>>>(x, b1, b2, b3, b4, ws, slots, out);
}

// Round 15
// 180.328 us; speedup vs baseline: 1.3449x; 1.3449x over previous
//
#include <hip/hip_runtime.h>
#include <math.h>

#define DEV __device__ __forceinline__

typedef short s16x8 __attribute__((ext_vector_type(8)));
typedef float f32x4 __attribute__((ext_vector_type(4)));

// ---- ws dword layout ----
// [0..3]: reduction slots (bit patterns of non-negative floats)
static constexpr int W1S = 16;   // 64 per-out-row weight scales
static constexpr int W2S = 80;   // 32
static constexpr int W3S = 112;  // 32
static constexpr int W4S = 144;  // 5
static constexpr int F0  = 256;  // 18 A-fragments (weights), each 64 lanes x int4
// frag ids: 0..3 = A1[nt] | 4..11 = A2[mt*4+c] | 12..15 = A3[mt*2+c] | 16..17 = A4[c]

DEV float qbias(float b, float bs) {
    float q = rintf(b / bs);
    return fminf(fmaxf(q, -2.147483648e9f), 2.147483648e9f);
}

DEV unsigned short bf16b(float f) {  // values used are exact in bf16 -> truncate
    return (unsigned short)(__float_as_uint(f) >> 16);
}

DEV void reduceAndAtomicMax(float v, unsigned int* slot) {
    #pragma unroll
    for (int off = 32; off; off >>= 1) v = fmaxf(v, __shfl_xor(v, off));
    __shared__ float sm[16];
    const int wid = threadIdx.x >> 6;
    if ((threadIdx.x & 63) == 0) sm[wid] = v;
    __syncthreads();
    if (threadIdx.x == 0) {
        const int nw = blockDim.x >> 6;
        float m = sm[0];
        for (int i = 1; i < nw; i++) m = fmaxf(m, sm[i]);
        atomicMax(slot, __float_as_uint(m)); // non-negative: bit order == value order
    }
}

// ---- setup: quantize weights, emit k-permuted A-fragments (weights as MFMA A) ----
__global__ __launch_bounds__(256) void k_quantw(const float* __restrict__ W1,
                                                const float* __restrict__ W2,
                                                const float* __restrict__ W3,
                                                const float* __restrict__ W4,
                                                float* __restrict__ wsf) {
    __shared__ int wq1[64 * 16], wq2[32 * 64], wq3[32 * 32], wq4[5 * 32];
    int* wsi = (int*)wsf;
    const int t = threadIdx.x;
    if (t < 4) ((unsigned int*)wsf)[t] = 0u;

    const float* W = nullptr; int row = -1, cols = 0; int* dq = nullptr; float* dsc = nullptr;
    if (t < 64)       { W = W1; row = t;       cols = 16; dq = wq1 + row * 16; dsc = wsf + W1S + row; }
    else if (t < 96)  { W = W2; row = t - 64;  cols = 64; dq = wq2 + row * 64; dsc = wsf + W2S + row; }
    else if (t < 128) { W = W3; row = t - 96;  cols = 32; dq = wq3 + row * 32; dsc = wsf + W3S + row; }
    else if (t < 133) { W = W4; row = t - 128; cols = 32; dq = wq4 + row * 32; dsc = wsf + W4S + row; }
    if (row >= 0) {
        const float* src = W + row * cols;
        float m = 0.f;
        for (int i = 0; i < cols; i++) m = fmaxf(m, fabsf(src[i]));
        float s = fmaxf(m * (1.0f / 127.0f), 1e-8f);
        *dsc = s;
        for (int i = 0; i < cols; i++) {
            float q = fminf(fmaxf(rintf(src[i] / s), -128.f), 127.f);
            dq[i] = (int)q;
        }
    }
    __syncthreads();

    // A-fragment: lane l holds A[row = l&15][k = (l>>4)*8 + e].
    //  L1: k=8*grp+e -> feature (grp&1)*8 + e           (grp>>1 = hi/lo)
    //  L2/L3/L4 chunk c: k=8*grp+e -> feature 16c + 4*grp + (e&3)  (e>>2 = hi/lo)
    for (int sIdx = t; sIdx < 18 * 64; sIdx += 256) {
        const int f = sIdx >> 6, l = sIdx & 63;
        const int grp = l >> 4, li = l & 15;
        int dw[4];
        #pragma unroll
        for (int d = 0; d < 4; d++) {
            unsigned int hv[2];
            #pragma unroll
            for (int h = 0; h < 2; h++) {
                const int e = 2 * d + h;
                int wv;
                if (f < 4) {
                    wv = wq1[(f * 16 + li) * 16 + (grp & 1) * 8 + e];
                } else if (f < 12) {
                    int mt = (f - 4) >> 2, c = (f - 4) & 3;
                    wv = wq2[(mt * 16 + li) * 64 + 16 * c + 4 * grp + (e & 3)];
                } else if (f < 16) {
                    int mt = (f - 12) >> 1, c = (f - 12) & 1;
                    wv = wq3[(mt * 16 + li) * 32 + 16 * c + 4 * grp + (e & 3)];
                } else {
                    int c = f - 16;
                    wv = (li < 5) ? wq4[li * 32 + 16 * c + 4 * grp + (e & 3)] : 0;
                }
                hv[h] = bf16b((float)wv);
            }
            dw[d] = (int)(hv[0] | (hv[1] << 16));
        }
        ((int4*)(wsi + F0))[f * 64 + l] = make_int4(dw[0], dw[1], dw[2], dw[3]);
    }
}

// ---- K0: max|x| ----
__global__ __launch_bounds__(1024, 4) void k_absmax(const float4* __restrict__ x,
                                                    unsigned int* __restrict__ slots, int n4) {
    float m = 0.f;
    for (int i = blockIdx.x * blockDim.x + threadIdx.x; i < n4; i += gridDim.x * blockDim.x) {
        float4 v = x[i];
        m = fmaxf(m, fmaxf(fmaxf(fabsf(v.x), fabsf(v.y)), fmaxf(fabsf(v.z), fabsf(v.w))));
    }
    reduceAndAtomicMax(m, slots + 0);
}

// pack bf16 bits of two low16-zero floats into one dword: {b0>>16, b1>>16}
DEV int packhi(float q0, float q1) {
    return (int)__builtin_amdgcn_perm(__float_as_uint(q1), __float_as_uint(q0), 0x07060302u);
}

// quant(+relu) + truncation split, two values -> hi dword + lo dword.
// Upper clamp dropped: by scale construction h*inv_next <= 32767*(1+~1e-7) < 32767.5,
// so rint never exceeds 32767 (verified via absmax guard).
DEV void qsplit2(float a0, float a1, float2 c0, float2 c1, int& hw, int& lw) {
    float t0 = fmaf(a0, c0.x, c0.y);
    float t1 = fmaf(a1, c1.x, c1.y);
    float q0 = fmaxf(rintf(t0), 0.f);
    float q1 = fmaxf(rintf(t1), 0.f);
    float h0 = __uint_as_float(__float_as_uint(q0) & 0xFFFF0000u); // top 8 sig bits
    float h1 = __uint_as_float(__float_as_uint(q1) & 0xFFFF0000u);
    hw = packhi(h0, h1);
    lw = packhi(q0 - h0, q1 - h1);  // residual <= 7 sig bits, bf16-exact
}

DEV s16x8 mkfrag(f32x4 acc, const float2* cq) {
    int h01, h23, l01, l23;
    qsplit2(acc[0], acc[1], cq[0], cq[1], h01, l01);
    qsplit2(acc[2], acc[3], cq[2], cq[3], h23, l23);
    return __builtin_bit_cast(s16x8, make_int4(h01, h23, l01, l23));
}

// x-path: |v|*inv0 <= 32767*(1+eps) < 32767.5 by scale construction -> clamps never bind
DEV float qxsel(float v, float inv0, bool hi) {
    float q = rintf(v * inv0);
    float h = __uint_as_float(__float_as_uint(q) & 0xFFFF0000u);
    return hi ? h : (q - h);
}

// ---- staged forward (per-wave chain; WPB_/TPW_ set per stage kernel) ----
template <int STAGE, int WPB_, int TPW_>
DEV void stage_body(const float* __restrict__ x,
                    const float* __restrict__ b1, const float* __restrict__ b2,
                    const float* __restrict__ b3, const float* __restrict__ b4,
                    const float* __restrict__ wsf, unsigned int* __restrict__ slots,
                    float* __restrict__ out) {
    __shared__ float2 QA[64], QB[32], QC[32], QD[16];
    const int t = threadIdx.x;
    const int w = t >> 6, l = t & 63;
    const int grp = l >> 4, li = l & 15;

    const float s0 = fmaxf(__uint_as_float(slots[0]) * (1.f / 32767.f), 1e-8f);
    float s1 = 1.f, s2 = 1.f, s3 = 1.f;
    if (STAGE >= 2) s1 = fmaxf(__uint_as_float(slots[1]) * (1.f / 32767.f), 1e-8f);
    if (STAGE >= 3) s2 = fmaxf(__uint_as_float(slots[2]) * (1.f / 32767.f), 1e-8f);
    if (STAGE >= 4) s3 = fmaxf(__uint_as_float(slots[3]) * (1.f / 32767.f), 1e-8f);
    const float inv0 = 1.f / s0;
    const float inv1 = (STAGE >= 2) ? 1.f / s1 : 0.f;
    const float inv2 = (STAGE >= 3) ? 1.f / s2 : 0.f;
    const float inv3 = (STAGE >= 4) ? 1.f / s3 : 0.f;

    if (t < 64) {
        float bs = wsf[W1S + t] * s0; float bi = qbias(b1[t], bs) * bs;
        QA[t] = (STAGE == 1) ? make_float2(bs, bi) : make_float2(bs * inv1, bi * inv1);
    }
    if (STAGE >= 2 && t >= 64 && t < 96) {
        int i = t - 64;
        float bs = wsf[W2S + i] * s1; float bi = qbias(b2[i], bs) * bs;
        QB[i] = (STAGE == 2) ? make_float2(bs, bi) : make_float2(bs * inv2, bi * inv2);
    }
    if (STAGE >= 3 && t >= 96 && t < 128) {
        int i = t - 96;
        float bs = wsf[W3S + i] * s2; float bi = qbias(b3[i], bs) * bs;
        QC[i] = (STAGE == 3) ? make_float2(bs, bi) : make_float2(bs * inv3, bi * inv3);
    }
    if (STAGE >= 4 && t >= 128 && t < 144) {
        int i = t - 128;
        if (i < 5) { float bs = wsf[W4S + i] * s3; QD[i] = make_float2(bs, qbias(b4[i], bs) * bs); }
        else QD[i] = make_float2(0.f, 0.f);
    }
    __syncthreads();

    const int4* fr = (const int4*)((const int*)wsf + F0);
    s16x8 A1[4], A2[2][4], A3[2][2], A4[2];
    #pragma unroll
    for (int nt = 0; nt < 4; nt++) A1[nt] = __builtin_bit_cast(s16x8, fr[nt * 64 + l]);
    if (STAGE >= 2)
        #pragma unroll
        for (int mt = 0; mt < 2; mt++)
            #pragma unroll
            for (int c = 0; c < 4; c++) A2[mt][c] = __builtin_bit_cast(s16x8, fr[(4 + mt * 4 + c) * 64 + l]);
    if (STAGE >= 3)
        #pragma unroll
        for (int mt = 0; mt < 2; mt++)
            #pragma unroll
            for (int c = 0; c < 2; c++) A3[mt][c] = __builtin_bit_cast(s16x8, fr[(12 + mt * 2 + c) * 64 + l]);
    if (STAGE >= 4) {
        A4[0] = __builtin_bit_cast(s16x8, fr[16 * 64 + l]);
        A4[1] = __builtin_bit_cast(s16x8, fr[17 * 64 + l]);
    }

    float2 cq1[4][4], cq2[2][4], cq3[2][4], e4[4];
    if (STAGE >= 2)
        #pragma unroll
        for (int nt = 0; nt < 4; nt++)
            #pragma unroll
            for (int r = 0; r < 4; r++) cq1[nt][r] = QA[16 * nt + 4 * grp + r];
    if (STAGE >= 3)
        #pragma unroll
        for (int mt = 0; mt < 2; mt++)
            #pragma unroll
            for (int r = 0; r < 4; r++) cq2[mt][r] = QB[16 * mt + 4 * grp + r];
    if (STAGE >= 4) {
        #pragma unroll
        for (int mt = 0; mt < 2; mt++)
            #pragma unroll
            for (int r = 0; r < 4; r++) cq3[mt][r] = QC[16 * mt + 4 * grp + r];
        #pragma unroll
        for (int r = 0; r < 4; r++) e4[r] = QD[4 * grp + r];
    }

    float ma1[4][4], ma2[2][4], ma3[2][4];
    if (STAGE == 1)
        #pragma unroll
        for (int nt = 0; nt < 4; nt++)
            #pragma unroll
            for (int r = 0; r < 4; r++) ma1[nt][r] = -3.402823466e38f;
    if (STAGE == 2)
        #pragma unroll
        for (int mt = 0; mt < 2; mt++)
            #pragma unroll
            for (int r = 0; r < 4; r++) ma2[mt][r] = -3.402823466e38f;
    if (STAGE == 3)
        #pragma unroll
        for (int mt = 0; mt < 2; mt++)
            #pragma unroll
            for (int r = 0; r < 4; r++) ma3[mt][r] = -3.402823466e38f;

    const bool hiLane = (grp < 2);
    const size_t tile0 = ((size_t)blockIdx.x * WPB_ + w) * (size_t)TPW_;

    // software prefetch of tile 0's x
    float4 px0, px1;
    {
        const float4* xr = (const float4*)(x + (tile0 * 16 + li) * 16 + (grp & 1) * 8);
        px0 = xr[0]; px1 = xr[1];
    }

    for (int it = 0; it < TPW_; ++it) {
        const size_t row0 = (tile0 + it) * 16;
        float4 v0 = px0, v1 = px1;
        if (it + 1 < TPW_) {  // issue next tile's loads early; compute below hides latency
            const float4* xr = (const float4*)(x + ((tile0 + it + 1) * 16 + li) * 16 + (grp & 1) * 8);
            px0 = xr[0]; px1 = xr[1];
        }

        // ---- B1 from x: col=li (batch), k=8*grp+e -> feature 8*(grp&1)+e, hi/lo=grp>>1
        s16x8 b1v;
        {
            float p0 = qxsel(v0.x, inv0, hiLane), p1 = qxsel(v0.y, inv0, hiLane);
            float p2 = qxsel(v0.z, inv0, hiLane), p3 = qxsel(v0.w, inv0, hiLane);
            float p4 = qxsel(v1.x, inv0, hiLane), p5 = qxsel(v1.y, inv0, hiLane);
            float p6 = qxsel(v1.z, inv0, hiLane), p7 = qxsel(v1.w, inv0, hiLane);
            b1v = __builtin_bit_cast(s16x8,
                make_int4(packhi(p0, p1), packhi(p2, p3), packhi(p4, p5), packhi(p6, p7)));
        }

        // ---- L1: D1[nt] lane holds (batch li, feature 16nt+4grp+r) ----
        s16x8 B2f[4];
        #pragma unroll
        for (int nt = 0; nt < 4; nt++) {
            f32x4 acc = {0.f, 0.f, 0.f, 0.f};
            acc = __builtin_amdgcn_mfma_f32_16x16x32_bf16(A1[nt], b1v, acc, 0, 0, 0);
            if constexpr (STAGE == 1) {
                #pragma unroll
                for (int r = 0; r < 4; r++) ma1[nt][r] = fmaxf(ma1[nt][r], acc[r]);
            } else {
                B2f[nt] = mkfrag(acc, cq1[nt]);
            }
        }
        if constexpr (STAGE == 1) continue;

        // ---- L2: chunk c consumes D1-tile nt=c ----
        f32x4 acc2[2] = {{0.f, 0.f, 0.f, 0.f}, {0.f, 0.f, 0.f, 0.f}};
        #pragma unroll
        for (int c = 0; c < 4; c++) {
            acc2[0] = __builtin_amdgcn_mfma_f32_16x16x32_bf16(A2[0][c], B2f[c], acc2[0], 0, 0, 0);
            acc2[1] = __builtin_amdgcn_mfma_f32_16x16x32_bf16(A2[1][c], B2f[c], acc2[1], 0, 0, 0);
        }
        if constexpr (STAGE == 2) {
            #pragma unroll
            for (int mt = 0; mt < 2; mt++)
                #pragma unroll
                for (int r = 0; r < 4; r++) ma2[mt][r] = fmaxf(ma2[mt][r], acc2[mt][r]);
            continue;
        }

        if constexpr (STAGE >= 3) {
            s16x8 B3f[2];
            #pragma unroll
            for (int c = 0; c < 2; c++) B3f[c] = mkfrag(acc2[c], cq2[c]);

            f32x4 acc3[2] = {{0.f, 0.f, 0.f, 0.f}, {0.f, 0.f, 0.f, 0.f}};
            #pragma unroll
            for (int c = 0; c < 2; c++) {
                acc3[0] = __builtin_amdgcn_mfma_f32_16x16x32_bf16(A3[0][c], B3f[c], acc3[0], 0, 0, 0);
                acc3[1] = __builtin_amdgcn_mfma_f32_16x16x32_bf16(A3[1][c], B3f[c], acc3[1], 0, 0, 0);
            }
            if constexpr (STAGE == 3) {
                #pragma unroll
                for (int mt = 0; mt < 2; mt++)
                    #pragma unroll
                    for (int r = 0; r < 4; r++) ma3[mt][r] = fmaxf(ma3[mt][r], acc3[mt][r]);
                continue;
            }

            if constexpr (STAGE == 4) {
                s16x8 B4f[2];
                #pragma unroll
                for (int c = 0; c < 2; c++) B4f[c] = mkfrag(acc3[c], cq3[c]);

                f32x4 acc4 = {0.f, 0.f, 0.f, 0.f};
                acc4 = __builtin_amdgcn_mfma_f32_16x16x32_bf16(A4[0], B4f[0], acc4, 0, 0, 0);
                acc4 = __builtin_amdgcn_mfma_f32_16x16x32_bf16(A4[1], B4f[1], acc4, 0, 0, 0);

                float lg0 = fmaf(acc4[0], e4[0].x, e4[0].y);
                float lg1 = fmaf(acc4[1], e4[1].x, e4[1].y);
                float lg2 = fmaf(acc4[2], e4[2].x, e4[2].y);
                float lg3 = fmaf(acc4[3], e4[3].x, e4[3].y);
                float lg4 = __shfl(lg0, li + 16);  // grp1 reg0 = feature 4

                if (l < 16) {
                    float m = fmaxf(fmaxf(fmaxf(lg0, lg1), fmaxf(lg2, lg3)), lg4);
                    float e0 = __expf(lg0 - m), e1 = __expf(lg1 - m), e2 = __expf(lg2 - m),
                          e3 = __expf(lg3 - m), ee4 = __expf(lg4 - m);
                    float r = 1.f / (e0 + e1 + e2 + e3 + ee4);
                    float* dst = out + (row0 + l) * 5;
                    dst[0] = e0 * r; dst[1] = e1 * r; dst[2] = e2 * r; dst[3] = e3 * r; dst[4] = ee4 * r;
                }
            }
        }
    }

    if (STAGE == 1) {
        float vmax = 0.f;
        #pragma unroll
        for (int nt = 0; nt < 4; nt++)
            #pragma unroll
            for (int r = 0; r < 4; r++) {
                float2 c = QA[16 * nt + 4 * grp + r];
                vmax = fmaxf(vmax, fmaf(ma1[nt][r], c.x, c.y));
            }
        reduceAndAtomicMax(vmax, slots + 1);
    } else if (STAGE == 2) {
        float vmax = 0.f;
        #pragma unroll
        for (int mt = 0; mt < 2; mt++)
            #pragma unroll
            for (int r = 0; r < 4; r++) {
                float2 c = QB[16 * mt + 4 * grp + r];
                vmax = fmaxf(vmax, fmaf(ma2[mt][r], c.x, c.y));
            }
        reduceAndAtomicMax(vmax, slots + 2);
    } else if (STAGE == 3) {
        float vmax = 0.f;
        #pragma unroll
        for (int mt = 0; mt < 2; mt++)
            #pragma unroll
            for (int r = 0; r < 4; r++) {
                float2 c = QC[16 * mt + 4 * grp + r];
                vmax = fmaxf(vmax, fmaf(ma3[mt][r], c.x, c.y));
            }
        reduceAndAtomicMax(vmax, slots + 3);
    }
}

// s1-s2: 1024-thread blocks (fragments fit the 64+64 reg split)
__global__ __launch_bounds__(1024, 4) void k_s1(const float* x, const float* b1, const float* b2,
                                                const float* b3, const float* b4, const float* ws,
                                                unsigned int* slots, float* out) {
    stage_body<1, 16, 8>(x, b1, b2, b3, b4, ws, slots, out);
}
__global__ __launch_bounds__(1024, 4) void k_s2(const float* x, const float* b1, const float* b2,
                                                const float* b3, const float* b4, const float* ws,
                                                unsigned int* slots, float* out) {
    stage_body<2, 16, 8>(x, b1, b2, b3, b4, ws, slots, out);
}
// s3, s4: 512-thread blocks, 256-reg budget (no spill), TPW=8 -> 1024 blocks
__global__ __launch_bounds__(512, 2) void k_s3(const float* x, const float* b1, const float* b2,
                                               const float* b3, const float* b4, const float* ws,
                                               unsigned int* slots, float* out) {
    stage_body<3, 8, 8>(x, b1, b2, b3, b4, ws, slots, out);
}
__global__ __launch_bounds__(512, 2) void k_s4(const float* x, const float* b1, const float* b2,
                                               const float* b3, const float* b4, const float* ws,
                                               unsigned int* slots, float* out) {
    stage_body<4, 8, 8>(x, b1, b2, b3, b4, ws, slots, out);
}

extern "C" void kernel_launch(void* const* d_in, const int* in_sizes, int n_in,
                              void* d_out, int out_size, void* d_ws, size_t ws_size,
                              hipStream_t stream) {
    const float* x  = (const float*)d_in[0];
    const float* W1 = (const float*)d_in[1];
    const float* b1 = (const float*)d_in[2];
    const float* W2 = (const float*)d_in[3];
    const float* b2 = (const float*)d_in[4];
    const float* W3 = (const float*)d_in[5];
    const float* b3 = (const float*)d_in[6];
    const float* W4 = (const float*)d_in[7];
    const float* b4 = (const float*)d_in[8];
    float* out = (float*)d_out;
    float* ws = (float*)d_ws;
    unsigned int* slots = (unsigned int*)d_ws;

    const int B = in_sizes[0] / 16;                       // 1 << 20 rows
    const int blocks12 = B / (16 * 8 * 16);               // 512
    const int blocks34 = B / (8 * 8 * 16);                // 1024

    k_quantw<<<1, 256, 0, stream>>>(W1, W2, W3, W4, ws);
    k_absmax<<<512, 1024, 0, stream>>>((const float4*)x, slots, in_sizes[0] / 4);
    k_s1<<<blocks12, 1024, 0, stream>>>(x, b1, b2, b3, b4, ws, slots, out);
    k_s2<<<blocks12, 1024, 0, stream>>>(x, b1, b2, b3, b4, ws, slots, out);
    k_s3<<<blocks34, 512, 0, stream>>>(x, b1, b2, b3, b4, ws, slots, out);
    k_s4<<<blocks34, 512, 0, stream>>>(x, b1, b2, b3, b4, ws, slots, out);
}

// Round 16
// 163.159 us; speedup vs baseline: 1.4865x; 1.1052x over previous
//
#include <hip/hip_runtime.h>
#include <math.h>

#define DEV __device__ __forceinline__

typedef short s16x8 __attribute__((ext_vector_type(8)));
typedef float f32x4 __attribute__((ext_vector_type(4)));

// ---- ws dword layout ----
// [0..3]: reduction slots (bit patterns of non-negative floats)
static constexpr int W1S = 16;   // 64 per-out-row weight scales
static constexpr int W2S = 80;   // 32
static constexpr int W3S = 112;  // 32
static constexpr int W4S = 144;  // 5
static constexpr int F0  = 256;  // 18 A-fragments (weights), each 64 lanes x int4
// frag ids: 0..3 = A1[nt] | 4..11 = A2[mt*4+c] | 12..15 = A3[mt*2+c] | 16..17 = A4[c]

DEV float qbias(float b, float bs) {
    float q = rintf(b / bs);
    return fminf(fmaxf(q, -2.147483648e9f), 2.147483648e9f);
}

DEV unsigned short bf16b(float f) {  // values used are exact in bf16 -> truncate
    return (unsigned short)(__float_as_uint(f) >> 16);
}

DEV void reduceAndAtomicMax(float v, unsigned int* slot) {
    #pragma unroll
    for (int off = 32; off; off >>= 1) v = fmaxf(v, __shfl_xor(v, off));
    __shared__ float sm[16];
    const int wid = threadIdx.x >> 6;
    if ((threadIdx.x & 63) == 0) sm[wid] = v;
    __syncthreads();
    if (threadIdx.x == 0) {
        const int nw = blockDim.x >> 6;
        float m = sm[0];
        for (int i = 1; i < nw; i++) m = fmaxf(m, sm[i]);
        atomicMax(slot, __float_as_uint(m)); // non-negative: bit order == value order
    }
}

// ---- setup: quantize weights, emit k-permuted A-fragments (weights as MFMA A) ----
__global__ __launch_bounds__(256) void k_quantw(const float* __restrict__ W1,
                                                const float* __restrict__ W2,
                                                const float* __restrict__ W3,
                                                const float* __restrict__ W4,
                                                float* __restrict__ wsf) {
    __shared__ int wq1[64 * 16], wq2[32 * 64], wq3[32 * 32], wq4[5 * 32];
    int* wsi = (int*)wsf;
    const int t = threadIdx.x;
    if (t < 4) ((unsigned int*)wsf)[t] = 0u;

    const float* W = nullptr; int row = -1, cols = 0; int* dq = nullptr; float* dsc = nullptr;
    if (t < 64)       { W = W1; row = t;       cols = 16; dq = wq1 + row * 16; dsc = wsf + W1S + row; }
    else if (t < 96)  { W = W2; row = t - 64;  cols = 64; dq = wq2 + row * 64; dsc = wsf + W2S + row; }
    else if (t < 128) { W = W3; row = t - 96;  cols = 32; dq = wq3 + row * 32; dsc = wsf + W3S + row; }
    else if (t < 133) { W = W4; row = t - 128; cols = 32; dq = wq4 + row * 32; dsc = wsf + W4S + row; }
    if (row >= 0) {
        const float* src = W + row * cols;
        float m = 0.f;
        for (int i = 0; i < cols; i++) m = fmaxf(m, fabsf(src[i]));
        float s = fmaxf(m * (1.0f / 127.0f), 1e-8f);
        *dsc = s;
        for (int i = 0; i < cols; i++) {
            float q = fminf(fmaxf(rintf(src[i] / s), -128.f), 127.f);
            dq[i] = (int)q;
        }
    }
    __syncthreads();

    // A-fragment: lane l holds A[row = l&15][k = (l>>4)*8 + e].
    //  L1: k=8*grp+e -> feature (grp&1)*8 + e           (grp>>1 = hi/lo)
    //  L2/L3/L4 chunk c: k=8*grp+e -> feature 16c + 4*grp + (e&3)  (e>>2 = hi/lo)
    for (int sIdx = t; sIdx < 18 * 64; sIdx += 256) {
        const int f = sIdx >> 6, l = sIdx & 63;
        const int grp = l >> 4, li = l & 15;
        int dw[4];
        #pragma unroll
        for (int d = 0; d < 4; d++) {
            unsigned int hv[2];
            #pragma unroll
            for (int h = 0; h < 2; h++) {
                const int e = 2 * d + h;
                int wv;
                if (f < 4) {
                    wv = wq1[(f * 16 + li) * 16 + (grp & 1) * 8 + e];
                } else if (f < 12) {
                    int mt = (f - 4) >> 2, c = (f - 4) & 3;
                    wv = wq2[(mt * 16 + li) * 64 + 16 * c + 4 * grp + (e & 3)];
                } else if (f < 16) {
                    int mt = (f - 12) >> 1, c = (f - 12) & 1;
                    wv = wq3[(mt * 16 + li) * 32 + 16 * c + 4 * grp + (e & 3)];
                } else {
                    int c = f - 16;
                    wv = (li < 5) ? wq4[li * 32 + 16 * c + 4 * grp + (e & 3)] : 0;
                }
                hv[h] = bf16b((float)wv);
            }
            dw[d] = (int)(hv[0] | (hv[1] << 16));
        }
        ((int4*)(wsi + F0))[f * 64 + l] = make_int4(dw[0], dw[1], dw[2], dw[3]);
    }
}

// ---- K0: max|x| ----
__global__ __launch_bounds__(1024, 4) void k_absmax(const float4* __restrict__ x,
                                                    unsigned int* __restrict__ slots, int n4) {
    float m = 0.f;
    for (int i = blockIdx.x * blockDim.x + threadIdx.x; i < n4; i += gridDim.x * blockDim.x) {
        float4 v = x[i];
        m = fmaxf(m, fmaxf(fmaxf(fabsf(v.x), fabsf(v.y)), fmaxf(fabsf(v.z), fabsf(v.w))));
    }
    reduceAndAtomicMax(m, slots + 0);
}

// pack bf16 bits of two low16-zero floats into one dword: {b0>>16, b1>>16}
DEV int packhi(float q0, float q1) {
    return (int)__builtin_amdgcn_perm(__float_as_uint(q1), __float_as_uint(q0), 0x07060302u);
}

// quant(+relu) + truncation split, two values -> hi dword + lo dword.
// Upper clamp dropped: by scale construction h*inv_next <= 32767*(1+~1e-7) < 32767.5,
// so rint never exceeds 32767 (validated: absmax unchanged in r15).
DEV void qsplit2(float a0, float a1, float2 c0, float2 c1, int& hw, int& lw) {
    float t0 = fmaf(a0, c0.x, c0.y);
    float t1 = fmaf(a1, c1.x, c1.y);
    float q0 = fmaxf(rintf(t0), 0.f);
    float q1 = fmaxf(rintf(t1), 0.f);
    float h0 = __uint_as_float(__float_as_uint(q0) & 0xFFFF0000u); // top 8 sig bits
    float h1 = __uint_as_float(__float_as_uint(q1) & 0xFFFF0000u);
    hw = packhi(h0, h1);
    lw = packhi(q0 - h0, q1 - h1);  // residual <= 7 sig bits, bf16-exact
}

DEV s16x8 mkfrag(f32x4 acc, const float2* cq) {
    int h01, h23, l01, l23;
    qsplit2(acc[0], acc[1], cq[0], cq[1], h01, l01);
    qsplit2(acc[2], acc[3], cq[2], cq[3], h23, l23);
    return __builtin_bit_cast(s16x8, make_int4(h01, h23, l01, l23));
}

// x-path: |v|*inv0 <= 32767*(1+eps) < 32767.5 by scale construction -> clamps never bind
DEV float qxsel(float v, float inv0, bool hi) {
    float q = rintf(v * inv0);
    float h = __uint_as_float(__float_as_uint(q) & 0xFFFF0000u);
    return hi ? h : (q - h);
}

// ---- staged forward (per-wave chain; WPB_/TPW_ set per stage kernel) ----
template <int STAGE, int WPB_, int TPW_>
DEV void stage_body(const float* __restrict__ x,
                    const float* __restrict__ b1, const float* __restrict__ b2,
                    const float* __restrict__ b3, const float* __restrict__ b4,
                    const float* __restrict__ wsf, unsigned int* __restrict__ slots,
                    float* __restrict__ out) {
    __shared__ float2 QA[64], QB[32], QC[32], QD[16];
    const int t = threadIdx.x;
    const int w = t >> 6, l = t & 63;
    const int grp = l >> 4, li = l & 15;

    const float s0 = fmaxf(__uint_as_float(slots[0]) * (1.f / 32767.f), 1e-8f);
    float s1 = 1.f, s2 = 1.f, s3 = 1.f;
    if (STAGE >= 2) s1 = fmaxf(__uint_as_float(slots[1]) * (1.f / 32767.f), 1e-8f);
    if (STAGE >= 3) s2 = fmaxf(__uint_as_float(slots[2]) * (1.f / 32767.f), 1e-8f);
    if (STAGE >= 4) s3 = fmaxf(__uint_as_float(slots[3]) * (1.f / 32767.f), 1e-8f);
    const float inv0 = 1.f / s0;
    const float inv1 = (STAGE >= 2) ? 1.f / s1 : 0.f;
    const float inv2 = (STAGE >= 3) ? 1.f / s2 : 0.f;
    const float inv3 = (STAGE >= 4) ? 1.f / s3 : 0.f;

    if (t < 64) {
        float bs = wsf[W1S + t] * s0; float bi = qbias(b1[t], bs) * bs;
        QA[t] = (STAGE == 1) ? make_float2(bs, bi) : make_float2(bs * inv1, bi * inv1);
    }
    if (STAGE >= 2 && t >= 64 && t < 96) {
        int i = t - 64;
        float bs = wsf[W2S + i] * s1; float bi = qbias(b2[i], bs) * bs;
        QB[i] = (STAGE == 2) ? make_float2(bs, bi) : make_float2(bs * inv2, bi * inv2);
    }
    if (STAGE >= 3 && t >= 96 && t < 128) {
        int i = t - 96;
        float bs = wsf[W3S + i] * s2; float bi = qbias(b3[i], bs) * bs;
        QC[i] = (STAGE == 3) ? make_float2(bs, bi) : make_float2(bs * inv3, bi * inv3);
    }
    if (STAGE >= 4 && t >= 128 && t < 144) {
        int i = t - 128;
        if (i < 5) { float bs = wsf[W4S + i] * s3; QD[i] = make_float2(bs, qbias(b4[i], bs) * bs); }
        else QD[i] = make_float2(0.f, 0.f);
    }
    __syncthreads();

    const int4* fr = (const int4*)((const int*)wsf + F0);
    s16x8 A1[4], A2[2][4], A3[2][2], A4[2];
    #pragma unroll
    for (int nt = 0; nt < 4; nt++) A1[nt] = __builtin_bit_cast(s16x8, fr[nt * 64 + l]);
    if (STAGE >= 2)
        #pragma unroll
        for (int mt = 0; mt < 2; mt++)
            #pragma unroll
            for (int c = 0; c < 4; c++) A2[mt][c] = __builtin_bit_cast(s16x8, fr[(4 + mt * 4 + c) * 64 + l]);
    if (STAGE >= 3)
        #pragma unroll
        for (int mt = 0; mt < 2; mt++)
            #pragma unroll
            for (int c = 0; c < 2; c++) A3[mt][c] = __builtin_bit_cast(s16x8, fr[(12 + mt * 2 + c) * 64 + l]);
    if (STAGE >= 4) {
        A4[0] = __builtin_bit_cast(s16x8, fr[16 * 64 + l]);
        A4[1] = __builtin_bit_cast(s16x8, fr[17 * 64 + l]);
    }

    float2 cq1[4][4], cq2[2][4], cq3[2][4], e4[4];
    if (STAGE >= 2)
        #pragma unroll
        for (int nt = 0; nt < 4; nt++)
            #pragma unroll
            for (int r = 0; r < 4; r++) cq1[nt][r] = QA[16 * nt + 4 * grp + r];
    if (STAGE >= 3)
        #pragma unroll
        for (int mt = 0; mt < 2; mt++)
            #pragma unroll
            for (int r = 0; r < 4; r++) cq2[mt][r] = QB[16 * mt + 4 * grp + r];
    if (STAGE >= 4) {
        #pragma unroll
        for (int mt = 0; mt < 2; mt++)
            #pragma unroll
            for (int r = 0; r < 4; r++) cq3[mt][r] = QC[16 * mt + 4 * grp + r];
        #pragma unroll
        for (int r = 0; r < 4; r++) e4[r] = QD[4 * grp + r];
    }

    float ma1[4][4], ma2[2][4], ma3[2][4];
    if (STAGE == 1)
        #pragma unroll
        for (int nt = 0; nt < 4; nt++)
            #pragma unroll
            for (int r = 0; r < 4; r++) ma1[nt][r] = -3.402823466e38f;
    if (STAGE == 2)
        #pragma unroll
        for (int mt = 0; mt < 2; mt++)
            #pragma unroll
            for (int r = 0; r < 4; r++) ma2[mt][r] = -3.402823466e38f;
    if (STAGE == 3)
        #pragma unroll
        for (int mt = 0; mt < 2; mt++)
            #pragma unroll
            for (int r = 0; r < 4; r++) ma3[mt][r] = -3.402823466e38f;

    const bool hiLane = (grp < 2);
    const size_t tile0 = ((size_t)blockIdx.x * WPB_ + w) * (size_t)TPW_;

    // software prefetch of tile 0's x
    float4 px0, px1;
    {
        const float4* xr = (const float4*)(x + (tile0 * 16 + li) * 16 + (grp & 1) * 8);
        px0 = xr[0]; px1 = xr[1];
    }

    for (int it = 0; it < TPW_; ++it) {
        const size_t row0 = (tile0 + it) * 16;
        float4 v0 = px0, v1 = px1;
        if (it + 1 < TPW_) {  // issue next tile's loads early; compute below hides latency
            const float4* xr = (const float4*)(x + ((tile0 + it + 1) * 16 + li) * 16 + (grp & 1) * 8);
            px0 = xr[0]; px1 = xr[1];
        }

        // ---- B1 from x: col=li (batch), k=8*grp+e -> feature 8*(grp&1)+e, hi/lo=grp>>1
        s16x8 b1v;
        {
            float p0 = qxsel(v0.x, inv0, hiLane), p1 = qxsel(v0.y, inv0, hiLane);
            float p2 = qxsel(v0.z, inv0, hiLane), p3 = qxsel(v0.w, inv0, hiLane);
            float p4 = qxsel(v1.x, inv0, hiLane), p5 = qxsel(v1.y, inv0, hiLane);
            float p6 = qxsel(v1.z, inv0, hiLane), p7 = qxsel(v1.w, inv0, hiLane);
            b1v = __builtin_bit_cast(s16x8,
                make_int4(packhi(p0, p1), packhi(p2, p3), packhi(p4, p5), packhi(p6, p7)));
        }

        // ---- L1: D1[nt] lane holds (batch li, feature 16nt+4grp+r) ----
        s16x8 B2f[4];
        #pragma unroll
        for (int nt = 0; nt < 4; nt++) {
            f32x4 acc = {0.f, 0.f, 0.f, 0.f};
            acc = __builtin_amdgcn_mfma_f32_16x16x32_bf16(A1[nt], b1v, acc, 0, 0, 0);
            if constexpr (STAGE == 1) {
                #pragma unroll
                for (int r = 0; r < 4; r++) ma1[nt][r] = fmaxf(ma1[nt][r], acc[r]);
            } else {
                B2f[nt] = mkfrag(acc, cq1[nt]);
            }
        }
        if constexpr (STAGE == 1) continue;

        // ---- L2: chunk c consumes D1-tile nt=c ----
        f32x4 acc2[2] = {{0.f, 0.f, 0.f, 0.f}, {0.f, 0.f, 0.f, 0.f}};
        #pragma unroll
        for (int c = 0; c < 4; c++) {
            acc2[0] = __builtin_amdgcn_mfma_f32_16x16x32_bf16(A2[0][c], B2f[c], acc2[0], 0, 0, 0);
            acc2[1] = __builtin_amdgcn_mfma_f32_16x16x32_bf16(A2[1][c], B2f[c], acc2[1], 0, 0, 0);
        }
        if constexpr (STAGE == 2) {
            #pragma unroll
            for (int mt = 0; mt < 2; mt++)
                #pragma unroll
                for (int r = 0; r < 4; r++) ma2[mt][r] = fmaxf(ma2[mt][r], acc2[mt][r]);
            continue;
        }

        if constexpr (STAGE >= 3) {
            s16x8 B3f[2];
            #pragma unroll
            for (int c = 0; c < 2; c++) B3f[c] = mkfrag(acc2[c], cq2[c]);

            f32x4 acc3[2] = {{0.f, 0.f, 0.f, 0.f}, {0.f, 0.f, 0.f, 0.f}};
            #pragma unroll
            for (int c = 0; c < 2; c++) {
                acc3[0] = __builtin_amdgcn_mfma_f32_16x16x32_bf16(A3[0][c], B3f[c], acc3[0], 0, 0, 0);
                acc3[1] = __builtin_amdgcn_mfma_f32_16x16x32_bf16(A3[1][c], B3f[c], acc3[1], 0, 0, 0);
            }
            if constexpr (STAGE == 3) {
                #pragma unroll
                for (int mt = 0; mt < 2; mt++)
                    #pragma unroll
                    for (int r = 0; r < 4; r++) ma3[mt][r] = fmaxf(ma3[mt][r], acc3[mt][r]);
                continue;
            }

            if constexpr (STAGE == 4) {
                s16x8 B4f[2];
                #pragma unroll
                for (int c = 0; c < 2; c++) B4f[c] = mkfrag(acc3[c], cq3[c]);

                f32x4 acc4 = {0.f, 0.f, 0.f, 0.f};
                acc4 = __builtin_amdgcn_mfma_f32_16x16x32_bf16(A4[0], B4f[0], acc4, 0, 0, 0);
                acc4 = __builtin_amdgcn_mfma_f32_16x16x32_bf16(A4[1], B4f[1], acc4, 0, 0, 0);

                float lg0 = fmaf(acc4[0], e4[0].x, e4[0].y);
                float lg1 = fmaf(acc4[1], e4[1].x, e4[1].y);
                float lg2 = fmaf(acc4[2], e4[2].x, e4[2].y);
                float lg3 = fmaf(acc4[3], e4[3].x, e4[3].y);
                float lg4 = __shfl(lg0, li + 16);  // grp1 reg0 = feature 4

                if (l < 16) {
                    float m = fmaxf(fmaxf(fmaxf(lg0, lg1), fmaxf(lg2, lg3)), lg4);
                    float e0 = __expf(lg0 - m), e1 = __expf(lg1 - m), e2 = __expf(lg2 - m),
                          e3 = __expf(lg3 - m), ee4 = __expf(lg4 - m);
                    float r = 1.f / (e0 + e1 + e2 + e3 + ee4);
                    float* dst = out + (row0 + l) * 5;
                    dst[0] = e0 * r; dst[1] = e1 * r; dst[2] = e2 * r; dst[3] = e3 * r; dst[4] = ee4 * r;
                }
            }
        }
    }

    if (STAGE == 1) {
        float vmax = 0.f;
        #pragma unroll
        for (int nt = 0; nt < 4; nt++)
            #pragma unroll
            for (int r = 0; r < 4; r++) {
                float2 c = QA[16 * nt + 4 * grp + r];
                vmax = fmaxf(vmax, fmaf(ma1[nt][r], c.x, c.y));
            }
        reduceAndAtomicMax(vmax, slots + 1);
    } else if (STAGE == 2) {
        float vmax = 0.f;
        #pragma unroll
        for (int mt = 0; mt < 2; mt++)
            #pragma unroll
            for (int r = 0; r < 4; r++) {
                float2 c = QB[16 * mt + 4 * grp + r];
                vmax = fmaxf(vmax, fmaf(ma2[mt][r], c.x, c.y));
            }
        reduceAndAtomicMax(vmax, slots + 2);
    } else if (STAGE == 3) {
        float vmax = 0.f;
        #pragma unroll
        for (int mt = 0; mt < 2; mt++)
            #pragma unroll
            for (int r = 0; r < 4; r++) {
                float2 c = QC[16 * mt + 4 * grp + r];
                vmax = fmaxf(vmax, fmaf(ma3[mt][r], c.x, c.y));
            }
        reduceAndAtomicMax(vmax, slots + 3);
    }
}

// s1-s2: 1024-thread blocks (fragments fit the 64+64 reg split)
__global__ __launch_bounds__(1024, 4) void k_s1(const float* x, const float* b1, const float* b2,
                                                const float* b3, const float* b4, const float* ws,
                                                unsigned int* slots, float* out) {
    stage_body<1, 16, 8>(x, b1, b2, b3, b4, ws, slots, out);
}
__global__ __launch_bounds__(1024, 4) void k_s2(const float* x, const float* b1, const float* b2,
                                                const float* b3, const float* b4, const float* ws,
                                                unsigned int* slots, float* out) {
    stage_body<2, 16, 8>(x, b1, b2, b3, b4, ws, slots, out);
}
// s3, s4: 512-thread blocks, 256-reg budget (no spill), TPW=16 -> 512 blocks (r13-proven)
__global__ __launch_bounds__(512, 2) void k_s3(const float* x, const float* b1, const float* b2,
                                               const float* b3, const float* b4, const float* ws,
                                               unsigned int* slots, float* out) {
    stage_body<3, 8, 16>(x, b1, b2, b3, b4, ws, slots, out);
}
__global__ __launch_bounds__(512, 2) void k_s4(const float* x, const float* b1, const float* b2,
                                               const float* b3, const float* b4, const float* ws,
                                               unsigned int* slots, float* out) {
    stage_body<4, 8, 16>(x, b1, b2, b3, b4, ws, slots, out);
}

extern "C" void kernel_launch(void* const* d_in, const int* in_sizes, int n_in,
                              void* d_out, int out_size, void* d_ws, size_t ws_size,
                              hipStream_t stream) {
    const float* x  = (const float*)d_in[0];
    const float* W1 = (const float*)d_in[1];
    const float* b1 = (const float*)d_in[2];
    const float* W2 = (const float*)d_in[3];
    const float* b2 = (const float*)d_in[4];
    const float* W3 = (const float*)d_in[5];
    const float* b3 = (const float*)d_in[6];
    const float* W4 = (const float*)d_in[7];
    const float* b4 = (const float*)d_in[8];
    float* out = (float*)d_out;
    float* ws = (float*)d_ws;
    unsigned int* slots = (unsigned int*)d_ws;

    const int B = in_sizes[0] / 16;                       // 1 << 20 rows
    const int blocks12 = B / (16 * 8 * 16);               // 512
    const int blocks34 = B / (8 * 16 * 16);               // 512

    k_quantw<<<1, 256, 0, stream>>>(W1, W2, W3, W4, ws);
    k_absmax<<<512, 1024, 0, stream>>>((const float4*)x, slots, in_sizes[0] / 4);
    k_s1<<<blocks12, 1024, 0, stream>>>(x, b1, b2, b3, b4, ws, slots, out);
    k_s2<<<blocks12, 1024, 0, stream>>>(x, b1, b2, b3, b4, ws, slots, out);
    k_s3<<<blocks34, 512, 0, stream>>>(x, b1, b2, b3, b4, ws, slots, out);
    k_s4<<<blocks34, 512, 0, stream>>>(x, b1, b2, b3, b4, ws, slots, out);
}